// Round 7
// baseline (3980.913 us; speedup 1.0000x reference)
//
#include <hip/hip_runtime.h>

#define NB 256
#define BLK 1024
#define TSn 95
#define DYn 90
#define DPn 80
#define DINn 170
#define Hn 4096

typedef unsigned int uint32;

// ---- ws byte offsets ----
#define B_W2T 0ull
#define B_W3T 33554432ull
#define B_W1T 67108864ull      // 4096 x 96 bf16 (u32[j][48])
#define B_UPB 67895296ull      // 95 x 2048 u32 (bf16x2)
#define B_H1M 68681728ull      // 64 mailboxes x 256 producers x 8 u32
#define B_H2M 69206016ull
#define B_L2M 69730304ull      // 64 mailboxes x 16 reducers x 48 u32
#define B_L1M 69926912ull      // 16 reducers x 16 producers x 48 u32
#define B_Y   69976064ull      // 96 x 96 f32
#define B_H1F 70012928ull      // u32[64][256]
#define B_H2F 70078464ull
#define B_L1F 70144000ull      // u32[16][16]
#define B_L2F 70145024ull      // u32[64][16]
#define WS_NEED 70149120ull
#define NFLAG_U32 34048        // (H1F..L2F) / 4

// out float offsets
#define O_YU 0
#define O_YL 8640
#define O_P1 17280
#define O_PU 24960
#define O_PL 32640

__device__ __forceinline__ uint32 ld_cgu(const uint32* p) {
  return __hip_atomic_load(p, __ATOMIC_RELAXED, __HIP_MEMORY_SCOPE_AGENT);
}
__device__ __forceinline__ void st_cgu(uint32* p, uint32 v) {
  __hip_atomic_store(p, v, __ATOMIC_RELAXED, __HIP_MEMORY_SCOPE_AGENT);
}
__device__ __forceinline__ unsigned f2bf(float f) {
  uint32 u = __float_as_uint(f);
  return (u + 0x7fffu + ((u >> 16) & 1u)) >> 16;  // RNE
}
__device__ __forceinline__ float bflo(uint32 u) { return __uint_as_float(u << 16); }
__device__ __forceinline__ float bfhi(uint32 u) { return __uint_as_float(u & 0xffff0000u); }

__device__ __forceinline__ float wred(float v) {
#pragma unroll
  for (int o = 32; o > 0; o >>= 1) v += __shfl_xor(v, o, 64);
  return v;
}

// Poll an epoch flag until it reaches target. Spin cap = escape hatch
// (garbage output instead of a hang if anything is ever wrong).
__device__ __forceinline__ void poll_ge(const uint32* p, uint32 target) {
  unsigned spins = 0;
  while (__hip_atomic_load(p, __ATOMIC_RELAXED, __HIP_MEMORY_SCOPE_AGENT) < target) {
    __builtin_amdgcn_s_sleep(2);
    if (++spins > (1u << 22)) break;
  }
}

// ---------------- prologue kernels ----------------
extern "C" __global__ void zero_flags(uint32* f) {
  int i = blockIdx.x * 256 + threadIdx.x;
  if (i < NFLAG_U32) f[i] = 0u;
}

// Transpose 4096x4096 f32 -> bf16x2-packed rows. grid 8192 (2 matrices).
extern "C" __global__ __launch_bounds__(256)
void t44_kernel(const float* __restrict__ W2, const float* __restrict__ W3,
                uint32* __restrict__ W2T, uint32* __restrict__ W3T) {
  const int mat = blockIdx.x >> 12;
  const int m = blockIdx.x & 4095;
  const float* src = mat ? W3 : W2;
  uint32* dst = mat ? W3T : W2T;
  const int j0 = (m >> 6) * 64, k0 = (m & 63) * 64;
  const int t = threadIdx.x;
  __shared__ float lds[64][65];
  const int jl = t & 63, kb = t >> 6;
#pragma unroll
  for (int i = 0; i < 16; ++i) {
    const int kl = kb + 4 * i;
    lds[kl][jl] = src[(size_t)(k0 + kl) * Hn + j0 + jl];
  }
  __syncthreads();
  const int kp = t & 31, jb = t >> 5;
#pragma unroll
  for (int i = 0; i < 8; ++i) {
    const int jr = jb + 8 * i;
    uint32 v = f2bf(lds[2 * kp][jr]) | (f2bf(lds[2 * kp + 1][jr]) << 16);
    dst[(size_t)(j0 + jr) * 2048 + (k0 >> 1) + kp] = v;
  }
}

// W1 y-part (rows q<90) -> W1T[j][q] bf16, stride 96 (zero-pad q>=90).
extern "C" __global__ __launch_bounds__(256)
void t1_kernel(const float* __restrict__ W1, unsigned short* __restrict__ W1T) {
  const int j0 = blockIdx.x * 64;
  const int t = threadIdx.x;
  const int jl = t & 63, q0 = t >> 6;
  for (int q = q0; q < 96; q += 4) {
    float v = (q < DYn) ? W1[(size_t)q * Hn + j0 + jl] : 0.f;
    W1T[(size_t)(j0 + jl) * 96 + q] = (unsigned short)f2bf(v);
  }
}

// UP[t][j] = b1[j] + u_t . W1[90:170][j], stored bf16x2-packed.
extern "C" __global__ __launch_bounds__(512)
void up_kernel(const float* __restrict__ J, const float* __restrict__ W1,
               const float* __restrict__ b1, uint32* __restrict__ UPb) {
  const int t = blockIdx.x >> 3, jc = blockIdx.x & 7;
  const int j = jc * 512 + threadIdx.x;
  __shared__ float us[DPn];
  __shared__ float oa[512];
  if (threadIdx.x < DPn) us[threadIdx.x] = J[(size_t)t * DINn + DYn + threadIdx.x];
  __syncthreads();
  float acc = b1[j];
#pragma unroll 8
  for (int k = 0; k < DPn; ++k) acc = fmaf(us[k], W1[(size_t)(DYn + k) * Hn + j], acc);
  oa[threadIdx.x] = acc;
  __syncthreads();
  if (threadIdx.x < 256)
    UPb[(size_t)t * 2048 + jc * 256 + threadIdx.x] =
        f2bf(oa[2 * threadIdx.x]) | (f2bf(oa[2 * threadIdx.x + 1]) << 16);
}

// ---------------- scan ----------------
__device__ __forceinline__ float dot_pf(const uint4* pf, const uint32* hvp, int l) {
  float a = 0.f;
#pragma unroll
  for (int i = 0; i < 8; ++i) {
    const uint4 hu = *(const uint4*)&hvp[i * 256 + l * 4];
    const uint4 u = pf[i];
    a = fmaf(bflo(hu.x), bflo(u.x), a); a = fmaf(bfhi(hu.x), bfhi(u.x), a);
    a = fmaf(bflo(hu.y), bflo(u.y), a); a = fmaf(bfhi(hu.y), bfhi(u.y), a);
    a = fmaf(bflo(hu.z), bflo(u.z), a); a = fmaf(bfhi(hu.z), bfhi(u.z), a);
    a = fmaf(bflo(hu.w), bflo(u.w), a); a = fmaf(bfhi(hu.w), bfhi(u.w), a);
  }
  return wred(a);
}

extern "C" __global__ __launch_bounds__(BLK, 1)
void scan4_kernel(const float* __restrict__ J, const float* __restrict__ b2,
                  const float* __restrict__ b3, const float* __restrict__ b4,
                  const float* __restrict__ W4, const uint32* __restrict__ W1Tu,
                  const uint32* __restrict__ W2T, const uint32* __restrict__ W3T,
                  const uint32* __restrict__ UPb,
                  uint32* __restrict__ H1M, uint32* __restrict__ H2M,
                  uint32* __restrict__ L1M, uint32* __restrict__ L2M,
                  uint32* __restrict__ H1F, uint32* __restrict__ H2F,
                  uint32* __restrict__ L1F, uint32* __restrict__ L2F,
                  float* __restrict__ Y) {
  const int bid = blockIdx.x, tid = threadIdx.x;
  const int w = tid >> 6, l = tid & 63;
  const int mc = bid & 63;       // mailbox index (4 blocks share one mailbox)
  const int j0 = bid * 16, j = j0 + w;

  __shared__ __align__(16) uint32 hvp[2048];
  __shared__ float2 ysp2[16][48];
  __shared__ float ys[96];
  __shared__ float h1s[16];
  __shared__ float h3L[16];
  __shared__ float y4L[96];
  __shared__ __align__(16) uint32 pk[8];
  __shared__ __align__(16) uint32 p4k[48];

  uint4 pf[8];
  {
    const uint4* wr = (const uint4*)W2T + (size_t)j * 512 + l;
#pragma unroll
    for (int i = 0; i < 8; ++i) pf[i] = wr[i * 64];
  }

  for (int t = 0; t <= TSn; ++t) {
    // ---- phase A: y_t ----
    if (t == 0) {
      if (tid < DYn) ys[tid] = J[tid];
    } else {
      if (tid < 16) poll_ge(L2F + mc * 16 + tid, (uint32)t);
      __syncthreads();
      if (l < 45) {
        uint32 v = ld_cgu(L2M + ((size_t)mc * 16 + w) * 48 + l);
        ysp2[w][l] = make_float2(bflo(v), bfhi(v));
      }
      __syncthreads();
      if (tid < 45) {
        float sx = 0.f, sy = 0.f;
#pragma unroll
        for (int r = 0; r < 16; ++r) { float2 p = ysp2[r][tid]; sx += p.x; sy += p.y; }
        ys[2 * tid] = b4[2 * tid] + sx;
        ys[2 * tid + 1] = b4[2 * tid + 1] + sy;
      }
    }
    __syncthreads();
    if (bid == 0 && tid < DYn) Y[(size_t)t * 96 + tid] = ys[tid];
    if (t == TSn) break;

    // ---- h1 slice (wave w -> column j), publish ----
    {
      float a = 0.f;
      if (l < 45) {
        uint32 u = W1Tu[(size_t)j * 48 + l];
        a = fmaf(ys[2 * l], bflo(u), ys[2 * l + 1] * bfhi(u));
      }
      a = wred(a);
      if (l == 0) {
        uint32 uu = UPb[(size_t)t * 2048 + (j >> 1)];
        float up = (j & 1) ? bfhi(uu) : bflo(uu);
        h1s[w] = fmaxf(up + a, 0.f);
      }
    }
    __syncthreads();
    if (tid < 8) pk[tid] = f2bf(h1s[2 * tid]) | (f2bf(h1s[2 * tid + 1]) << 16);
    __syncthreads();
    if (tid < 64) {
      uint32* mb = H1M + (size_t)tid * 2048 + bid * 8;
#pragma unroll
      for (int i = 0; i < 8; ++i) st_cgu(mb + i, pk[i]);
    }
    __syncthreads();  // hipcc drains vmcnt(0) before s_barrier -> payload accepted
    if (tid < 64) st_cgu(H1F + tid * 256 + bid, (uint32)(t + 1));

    // ---- phase B: h2 = relu(b2 + W2 . h1) ----
    if (tid < 256) poll_ge(H1F + mc * 256 + tid, (uint32)(t + 1));
    __syncthreads();
    hvp[tid] = ld_cgu(H1M + (size_t)mc * 2048 + tid);
    hvp[tid + 1024] = ld_cgu(H1M + (size_t)mc * 2048 + 1024 + tid);
    __syncthreads();
    {
      float a = dot_pf(pf, hvp, l);
      const uint4* wr = (const uint4*)W3T + (size_t)j * 512 + l;
#pragma unroll
      for (int i = 0; i < 8; ++i) pf[i] = wr[i * 64];
      if (l == 0) h1s[w] = fmaxf(b2[j] + a, 0.f);
    }
    __syncthreads();
    if (tid < 8) pk[tid] = f2bf(h1s[2 * tid]) | (f2bf(h1s[2 * tid + 1]) << 16);
    __syncthreads();
    if (tid < 64) {
      uint32* mb = H2M + (size_t)tid * 2048 + bid * 8;
#pragma unroll
      for (int i = 0; i < 8; ++i) st_cgu(mb + i, pk[i]);
    }
    __syncthreads();
    if (tid < 64) st_cgu(H2F + tid * 256 + bid, (uint32)(t + 1));

    // ---- phase C: h3 (local) + W4 partial -> L1 push; reducers -> L2 push ----
    if (tid < 256) poll_ge(H2F + mc * 256 + tid, (uint32)(t + 1));
    __syncthreads();
    hvp[tid] = ld_cgu(H2M + (size_t)mc * 2048 + tid);
    hvp[tid + 1024] = ld_cgu(H2M + (size_t)mc * 2048 + 1024 + tid);
    __syncthreads();
    {
      float a = dot_pf(pf, hvp, l);
      const uint4* wr = (const uint4*)W2T + (size_t)j * 512 + l;  // next step
#pragma unroll
      for (int i = 0; i < 8; ++i) pf[i] = wr[i * 64];
      if (l == 0) h3L[w] = fmaxf(b3[j] + a, 0.f);
    }
    __syncthreads();
    if (tid < DYn) {
      float acc = 0.f;
#pragma unroll
      for (int jj = 0; jj < 16; ++jj)
        acc = fmaf(h3L[jj], W4[(size_t)(j0 + jj) * DYn + tid], acc);
      y4L[tid] = acc;
    }
    __syncthreads();
    if (tid < 45) p4k[tid] = f2bf(y4L[2 * tid]) | (f2bf(y4L[2 * tid + 1]) << 16);
    else if (tid < 48) p4k[tid] = 0u;
    __syncthreads();
    if (tid < 48)
      st_cgu(L1M + ((size_t)(bid >> 4) * 16 + (bid & 15)) * 48 + tid, p4k[tid]);
    __syncthreads();
    if (tid == 0) st_cgu(L1F + (bid >> 4) * 16 + (bid & 15), (uint32)(t + 1));

    if (bid < 16) {  // reducer duty: gather 16 partials, push level-1 sum
      if (tid < 16) poll_ge(L1F + bid * 16 + tid, (uint32)(t + 1));
      __syncthreads();
      if (l < 45) {
        uint32 v = ld_cgu(L1M + ((size_t)bid * 16 + w) * 48 + l);
        ysp2[w][l] = make_float2(bflo(v), bfhi(v));
      }
      __syncthreads();
      if (tid < 45) {
        float sx = 0.f, sy = 0.f;
#pragma unroll
        for (int r = 0; r < 16; ++r) { float2 p = ysp2[r][tid]; sx += p.x; sy += p.y; }
        p4k[tid] = f2bf(sx) | (f2bf(sy) << 16);
      } else if (tid < 48) p4k[tid] = 0u;
      __syncthreads();
      if (tid < 768) {
        const int c = tid / 12, q = tid - c * 12;
        uint32* d = L2M + (size_t)c * 768 + bid * 48 + q * 4;
        st_cgu(d + 0, p4k[q * 4]);     st_cgu(d + 1, p4k[q * 4 + 1]);
        st_cgu(d + 2, p4k[q * 4 + 2]); st_cgu(d + 3, p4k[q * 4 + 3]);
      }
      __syncthreads();
      if (tid < 64) st_cgu(L2F + tid * 16 + bid, (uint32)(t + 1));
    }
  }
}

// ---------------- epilogue ----------------
extern "C" __global__ void post_kernel(const float* __restrict__ J, const float* __restrict__ Pp,
                                       const float* __restrict__ UppY, const float* __restrict__ LowY,
                                       const float* __restrict__ UppP, const float* __restrict__ LowP,
                                       const float* __restrict__ scY, const float* __restrict__ mnY,
                                       const float* __restrict__ scP, const float* __restrict__ mnP,
                                       const float* __restrict__ Y, float* __restrict__ out) {
  const int t = blockIdx.x, k = threadIdx.x;
  if (k < DPn) {
    const float ph = fmaf(J[(size_t)t * DINn + DYn + k], scP[k], mnP[k]);
    out[O_P1 + t * DPn + k] = ph * Pp[t * DPn + k];
    out[O_PU + t * DPn + k] = fmaxf(ph - UppP[t * DPn + k], 0.f);
    out[O_PL + t * DPn + k] = fmaxf(LowP[t * DPn + k] - ph, 0.f);
  }
  if (k < DYn) {
    const float yh = fmaf(Y[(size_t)t * 96 + k], scY[k], mnY[k]);
    out[O_YU + t * DYn + k] = fmaxf(yh - UppY[t * DYn + k], 0.f);
    out[O_YL + t * DYn + k] = fmaxf(LowY[t * DYn + k] - yh, 0.f);
  }
}

extern "C" void kernel_launch(void* const* d_in, const int* in_sizes, int n_in,
                              void* d_out, int out_size, void* d_ws, size_t ws_size,
                              hipStream_t stream) {
  const float* J    = (const float*)d_in[0];
  const float* Pp   = (const float*)d_in[1];
  const float* UppY = (const float*)d_in[2];
  const float* LowY = (const float*)d_in[3];
  const float* UppP = (const float*)d_in[4];
  const float* LowP = (const float*)d_in[5];
  const float* W1   = (const float*)d_in[6];
  const float* b1   = (const float*)d_in[7];
  const float* W2   = (const float*)d_in[8];
  const float* b2   = (const float*)d_in[9];
  const float* W3   = (const float*)d_in[10];
  const float* b3   = (const float*)d_in[11];
  const float* W4   = (const float*)d_in[12];
  const float* b4   = (const float*)d_in[13];
  const float* scY  = (const float*)d_in[14];
  const float* mnY  = (const float*)d_in[15];
  const float* scP  = (const float*)d_in[16];
  const float* mnP  = (const float*)d_in[17];
  float* out = (float*)d_out;

  if (ws_size < WS_NEED) return;  // ws >= 70.72 MB proven in R4

  char* base = (char*)d_ws;
  uint32* W2T = (uint32*)(base + B_W2T);
  uint32* W3T = (uint32*)(base + B_W3T);
  uint32* W1Tu = (uint32*)(base + B_W1T);
  uint32* UPb = (uint32*)(base + B_UPB);
  uint32* H1M = (uint32*)(base + B_H1M);
  uint32* H2M = (uint32*)(base + B_H2M);
  uint32* L2M = (uint32*)(base + B_L2M);
  uint32* L1M = (uint32*)(base + B_L1M);
  float*  Y   = (float*)(base + B_Y);
  uint32* H1F = (uint32*)(base + B_H1F);
  uint32* H2F = (uint32*)(base + B_H2F);
  uint32* L1F = (uint32*)(base + B_L1F);
  uint32* L2F = (uint32*)(base + B_L2F);

  zero_flags<<<dim3(136), dim3(256), 0, stream>>>(H1F);
  t44_kernel<<<dim3(8192), dim3(256), 0, stream>>>(W2, W3, W2T, W3T);
  t1_kernel<<<dim3(64), dim3(256), 0, stream>>>(W1, (unsigned short*)W1Tu);
  up_kernel<<<dim3(TSn * 8), dim3(512), 0, stream>>>(J, W1, b1, UPb);
  scan4_kernel<<<dim3(NB), dim3(BLK), 0, stream>>>(
      J, b2, b3, b4, W4, W1Tu, W2T, W3T, UPb,
      H1M, H2M, L1M, L2M, H1F, H2F, L1F, L2F, Y);
  post_kernel<<<dim3(96), dim3(128), 0, stream>>>(
      J, Pp, UppY, LowY, UppP, LowP, scY, mnY, scP, mnP, Y, out);
}

// Round 8
// 2184.638 us; speedup vs baseline: 1.8222x; 1.8222x over previous
//
#include <hip/hip_runtime.h>

#define NB 256
#define BLK 1024
#define TSn 95
#define DYn 90
#define DPn 80
#define DINn 170
#define Hn 4096

typedef unsigned int uint32;
typedef unsigned long long uint64;

// ---- ws byte offsets ----
#define B_W2T 0ull             // 4096x4096 bf16 transposed (rows of 8KB)
#define B_W3T 33554432ull
#define B_W1T 67108864ull      // 4096 x 48 u32 (bf16x2 per q-pair)
#define B_UPB 67895296ull      // 95 x 2048 u32 (bf16x2)
#define B_H1X 68673536ull      // 256 x 8 u32
#define B_H2X 68681728ull      // 256 x 8 u32
#define B_P4X 68689920ull      // TRANSPOSED: 48 slots x 256 blocks u32
#define B_Y   68739072ull      // 96 x 96 f32
#define B_H1F 68775936ull      // 256 u32
#define B_H2F 68776960ull      // 256 u32
#define B_P4F 68777984ull      // 256 u32
#define WS_NEED 68779008ull

// out float offsets
#define O_YU 0
#define O_YL 8640
#define O_P1 17280
#define O_PU 24960
#define O_PL 32640

__device__ __forceinline__ uint64 ld_cg64(const uint64* p) {
  return __hip_atomic_load(p, __ATOMIC_RELAXED, __HIP_MEMORY_SCOPE_AGENT);
}
__device__ __forceinline__ void st_cgu(uint32* p, uint32 v) {
  __hip_atomic_store(p, v, __ATOMIC_RELAXED, __HIP_MEMORY_SCOPE_AGENT);
}
__device__ __forceinline__ unsigned f2bf(float f) {
  uint32 u = __float_as_uint(f);
  return (u + 0x7fffu + ((u >> 16) & 1u)) >> 16;  // RNE
}
__device__ __forceinline__ float bflo(uint32 u) { return __uint_as_float(u << 16); }
__device__ __forceinline__ float bfhi(uint32 u) { return __uint_as_float(u & 0xffff0000u); }

__device__ __forceinline__ float wred(float v) {
#pragma unroll
  for (int o = 32; o > 0; o >>= 1) v += __shfl_xor(v, o, 64);
  return v;
}

// Poll an epoch flag (monotone) until >= target. Spin cap = escape hatch.
__device__ __forceinline__ void poll_ge(const uint32* p, uint32 target) {
  unsigned spins = 0;
  while (__hip_atomic_load(p, __ATOMIC_RELAXED, __HIP_MEMORY_SCOPE_AGENT) < target) {
    __builtin_amdgcn_s_sleep(1);
    if (++spins > (1u << 22)) break;
  }
}

// ---------------- prologue kernels (proven R5-R7) ----------------
extern "C" __global__ void zero_flags(uint32* f) {
  int i = blockIdx.x * 256 + threadIdx.x;
  if (i < 768) f[i] = 0u;
}

extern "C" __global__ __launch_bounds__(256)
void t44_kernel(const float* __restrict__ W2, const float* __restrict__ W3,
                uint32* __restrict__ W2T, uint32* __restrict__ W3T) {
  const int mat = blockIdx.x >> 12;
  const int m = blockIdx.x & 4095;
  const float* src = mat ? W3 : W2;
  uint32* dst = mat ? W3T : W2T;
  const int j0 = (m >> 6) * 64, k0 = (m & 63) * 64;
  const int t = threadIdx.x;
  __shared__ float lds[64][65];
  const int jl = t & 63, kb = t >> 6;
#pragma unroll
  for (int i = 0; i < 16; ++i) {
    const int kl = kb + 4 * i;
    lds[kl][jl] = src[(size_t)(k0 + kl) * Hn + j0 + jl];
  }
  __syncthreads();
  const int kp = t & 31, jb = t >> 5;
#pragma unroll
  for (int i = 0; i < 8; ++i) {
    const int jr = jb + 8 * i;
    uint32 v = f2bf(lds[2 * kp][jr]) | (f2bf(lds[2 * kp + 1][jr]) << 16);
    dst[(size_t)(j0 + jr) * 2048 + (k0 >> 1) + kp] = v;
  }
}

// W1 y-part -> W1T[j][48] bf16x2 over q-pairs (zero-pad q>=90).
extern "C" __global__ __launch_bounds__(256)
void t1_kernel(const float* __restrict__ W1, uint32* __restrict__ W1Tu) {
  const int j0 = blockIdx.x * 64;
  const int t = threadIdx.x;
  const int jl = t & 63, q0 = t >> 6;
  for (int qp = q0; qp < 48; qp += 4) {
    float v0 = (2 * qp < DYn) ? W1[(size_t)(2 * qp) * Hn + j0 + jl] : 0.f;
    float v1 = (2 * qp + 1 < DYn) ? W1[(size_t)(2 * qp + 1) * Hn + j0 + jl] : 0.f;
    W1Tu[(size_t)(j0 + jl) * 48 + qp] = f2bf(v0) | (f2bf(v1) << 16);
  }
}

extern "C" __global__ __launch_bounds__(512)
void up_kernel(const float* __restrict__ J, const float* __restrict__ W1,
               const float* __restrict__ b1, uint32* __restrict__ UPb) {
  const int t = blockIdx.x >> 3, jc = blockIdx.x & 7;
  const int j = jc * 512 + threadIdx.x;
  __shared__ float us[DPn];
  __shared__ float oa[512];
  if (threadIdx.x < DPn) us[threadIdx.x] = J[(size_t)t * DINn + DYn + threadIdx.x];
  __syncthreads();
  float acc = b1[j];
#pragma unroll 8
  for (int k = 0; k < DPn; ++k) acc = fmaf(us[k], W1[(size_t)(DYn + k) * Hn + j], acc);
  oa[threadIdx.x] = acc;
  __syncthreads();
  if (threadIdx.x < 256)
    UPb[(size_t)t * 2048 + jc * 256 + threadIdx.x] =
        f2bf(oa[2 * threadIdx.x]) | (f2bf(oa[2 * threadIdx.x + 1]) << 16);
}

// ---------------- scan ----------------
__device__ __forceinline__ float dot_lds(const uint32* __restrict__ Wrow,
                                         const uint32* __restrict__ hvp, int l) {
  float a = 0.f;
#pragma unroll
  for (int i = 0; i < 8; ++i) {
    const uint4 u = *(const uint4*)&Wrow[i * 256 + l * 4];
    const uint4 h = *(const uint4*)&hvp[i * 256 + l * 4];
    a = fmaf(bflo(h.x), bflo(u.x), a); a = fmaf(bfhi(h.x), bfhi(u.x), a);
    a = fmaf(bflo(h.y), bflo(u.y), a); a = fmaf(bfhi(h.y), bfhi(u.y), a);
    a = fmaf(bflo(h.z), bflo(u.z), a); a = fmaf(bfhi(h.z), bfhi(u.z), a);
    a = fmaf(bflo(h.w), bflo(u.w), a); a = fmaf(bfhi(h.w), bfhi(u.w), a);
  }
  return wred(a);
}

__device__ __forceinline__ float dot_pf(const uint4* pf, const uint32* __restrict__ hvp, int l) {
  float a = 0.f;
#pragma unroll
  for (int i = 0; i < 8; ++i) {
    const uint4 h = *(const uint4*)&hvp[i * 256 + l * 4];
    const uint4 u = pf[i];
    a = fmaf(bflo(h.x), bflo(u.x), a); a = fmaf(bfhi(h.x), bfhi(u.x), a);
    a = fmaf(bflo(h.y), bflo(u.y), a); a = fmaf(bfhi(h.y), bfhi(u.y), a);
    a = fmaf(bflo(h.z), bflo(u.z), a); a = fmaf(bfhi(h.z), bfhi(u.z), a);
    a = fmaf(bflo(h.w), bflo(u.w), a); a = fmaf(bfhi(h.w), bfhi(u.w), a);
  }
  return wred(a);
}

extern "C" __global__ __launch_bounds__(BLK, 1)
void scan5_kernel(const float* __restrict__ J, const float* __restrict__ b2,
                  const float* __restrict__ b3, const float* __restrict__ b4,
                  const float* __restrict__ W4, const uint32* __restrict__ W1Tu,
                  const uint32* __restrict__ W2T, const uint32* __restrict__ W3T,
                  const uint32* __restrict__ UPb,
                  uint32* __restrict__ H1X, uint32* __restrict__ H2X,
                  uint32* __restrict__ P4X, uint32* __restrict__ H1F,
                  uint32* __restrict__ H2F, uint32* __restrict__ P4F,
                  float* __restrict__ Y) {
  const int bid = blockIdx.x, tid = threadIdx.x;
  const int w = tid >> 6, l = tid & 63;
  const int j0 = bid * 16, j = j0 + w;

  __shared__ __align__(16) uint32 W2L[16 * 2048];  // this block's 16 W2T rows, resident
  __shared__ __align__(16) uint32 hvp[2048];
  __shared__ float ys[96];
  __shared__ float h1s[16];
  __shared__ float h3L[16];
  __shared__ float y4L[96];

  // one-time stage: W2 rows -> LDS (coalesced, cached loads)
  {
    const uint32* src = W2T + (size_t)j0 * 2048;
    for (int k = tid; k < 32768; k += BLK) W2L[k] = src[k];
  }
  uint4 pf[8];
  __syncthreads();

  for (int t = 0; t <= TSn; ++t) {
    // ---- phase A: y_t (all blocks, symmetric) ----
    if (t == 0) {
      if (tid < DYn) ys[tid] = J[tid];
      __syncthreads();
    } else {
      if (tid < 256) poll_ge(P4F + tid, (uint32)t);
      __syncthreads();
      // gather-reduce P4X[48][256]: wave w handles slots 3w..3w+2, coalesced 1KB rows
#pragma unroll
      for (int ss = 0; ss < 3; ++ss) {
        const int s = w * 3 + ss;
        const uint64* pr = (const uint64*)(P4X + s * 256) + l * 2;
        uint64 u0 = ld_cg64(pr), u1 = ld_cg64(pr + 1);
        const uint32 a0 = (uint32)u0, a1 = (uint32)(u0 >> 32);
        const uint32 a2 = (uint32)u1, a3 = (uint32)(u1 >> 32);
        float sx = bflo(a0) + bflo(a1) + bflo(a2) + bflo(a3);
        float sy = bfhi(a0) + bfhi(a1) + bfhi(a2) + bfhi(a3);
        sx = wred(sx); sy = wred(sy);
        if (l == 0 && 2 * s < DYn) {
          ys[2 * s] = b4[2 * s] + sx;
          ys[2 * s + 1] = b4[2 * s + 1] + sy;
        }
      }
      __syncthreads();
    }
    if (bid == 0 && tid < DYn) Y[(size_t)t * 96 + tid] = ys[tid];
    if (t == TSn) break;

    // ---- h1 (16 owned cols) + publish ----
    {
      float a = 0.f;
      if (l < 45) {
        uint32 u = W1Tu[(size_t)j * 48 + l];
        a = fmaf(ys[2 * l], bflo(u), ys[2 * l + 1] * bfhi(u));
      }
      a = wred(a);
      if (l == 0) {
        uint32 uu = UPb[(size_t)t * 2048 + (j >> 1)];
        h1s[w] = fmaxf(((j & 1) ? bfhi(uu) : bflo(uu)) + a, 0.f);
      }
    }
    __syncthreads();
    if (tid < 8) st_cgu(H1X + bid * 8 + tid, f2bf(h1s[2 * tid]) | (f2bf(h1s[2 * tid + 1]) << 16));
    __syncthreads();  // vmcnt(0) drain -> payload globally issued before flag
    if (tid == 0) st_cgu(H1F + bid, (uint32)(t + 1));

    // ---- phase B: h2 from LDS-resident W2 ----
    {  // issue W3 prefetch BEFORE the poll: hop wait hides the stream
      const uint4* wr3 = (const uint4*)W3T + (size_t)j * 512 + l;
#pragma unroll
      for (int i = 0; i < 8; ++i) pf[i] = wr3[i * 64];
    }
    if (tid < 256) poll_ge(H1F + tid, (uint32)(t + 1));
    __syncthreads();
    ((uint64*)hvp)[tid] = ld_cg64((const uint64*)H1X + tid);
    __syncthreads();
    {
      float a = dot_lds(&W2L[w * 2048], hvp, l);
      if (l == 0) h1s[w] = fmaxf(b2[j] + a, 0.f);
    }
    __syncthreads();
    if (tid < 8) st_cgu(H2X + bid * 8 + tid, f2bf(h1s[2 * tid]) | (f2bf(h1s[2 * tid + 1]) << 16));
    __syncthreads();
    if (tid == 0) st_cgu(H2F + bid, (uint32)(t + 1));

    // ---- phase C: h3 (prefetched W3) + W4 partial -> P4X ----
    if (tid < 256) poll_ge(H2F + tid, (uint32)(t + 1));
    __syncthreads();
    ((uint64*)hvp)[tid] = ld_cg64((const uint64*)H2X + tid);
    __syncthreads();
    {
      float a = dot_pf(pf, hvp, l);
      if (l == 0) h3L[w] = fmaxf(b3[j] + a, 0.f);
    }
    __syncthreads();
    if (tid < DYn) {
      float acc = 0.f;
#pragma unroll
      for (int jj = 0; jj < 16; ++jj)
        acc = fmaf(h3L[jj], W4[(size_t)(j0 + jj) * DYn + tid], acc);
      y4L[tid] = acc;
    } else if (tid < 96) {
      y4L[tid] = 0.f;
    }
    __syncthreads();
    if (tid < 48)
      st_cgu(P4X + tid * 256 + bid, f2bf(y4L[2 * tid]) | (f2bf(y4L[2 * tid + 1]) << 16));
    __syncthreads();
    if (tid == 0) st_cgu(P4F + bid, (uint32)(t + 1));
  }
}

// ---------------- epilogue ----------------
extern "C" __global__ void post_kernel(const float* __restrict__ J, const float* __restrict__ Pp,
                                       const float* __restrict__ UppY, const float* __restrict__ LowY,
                                       const float* __restrict__ UppP, const float* __restrict__ LowP,
                                       const float* __restrict__ scY, const float* __restrict__ mnY,
                                       const float* __restrict__ scP, const float* __restrict__ mnP,
                                       const float* __restrict__ Y, float* __restrict__ out) {
  const int t = blockIdx.x, k = threadIdx.x;
  if (k < DPn) {
    const float ph = fmaf(J[(size_t)t * DINn + DYn + k], scP[k], mnP[k]);
    out[O_P1 + t * DPn + k] = ph * Pp[t * DPn + k];
    out[O_PU + t * DPn + k] = fmaxf(ph - UppP[t * DPn + k], 0.f);
    out[O_PL + t * DPn + k] = fmaxf(LowP[t * DPn + k] - ph, 0.f);
  }
  if (k < DYn) {
    const float yh = fmaf(Y[(size_t)t * 96 + k], scY[k], mnY[k]);
    out[O_YU + t * DYn + k] = fmaxf(yh - UppY[t * DYn + k], 0.f);
    out[O_YL + t * DYn + k] = fmaxf(LowY[t * DYn + k] - yh, 0.f);
  }
}

extern "C" void kernel_launch(void* const* d_in, const int* in_sizes, int n_in,
                              void* d_out, int out_size, void* d_ws, size_t ws_size,
                              hipStream_t stream) {
  const float* J    = (const float*)d_in[0];
  const float* Pp   = (const float*)d_in[1];
  const float* UppY = (const float*)d_in[2];
  const float* LowY = (const float*)d_in[3];
  const float* UppP = (const float*)d_in[4];
  const float* LowP = (const float*)d_in[5];
  const float* W1   = (const float*)d_in[6];
  const float* b1   = (const float*)d_in[7];
  const float* W2   = (const float*)d_in[8];
  const float* b2   = (const float*)d_in[9];
  const float* W3   = (const float*)d_in[10];
  const float* b3   = (const float*)d_in[11];
  const float* W4   = (const float*)d_in[12];
  const float* b4   = (const float*)d_in[13];
  const float* scY  = (const float*)d_in[14];
  const float* mnY  = (const float*)d_in[15];
  const float* scP  = (const float*)d_in[16];
  const float* mnP  = (const float*)d_in[17];
  float* out = (float*)d_out;

  if (ws_size < WS_NEED) return;

  char* base = (char*)d_ws;
  uint32* W2T  = (uint32*)(base + B_W2T);
  uint32* W3T  = (uint32*)(base + B_W3T);
  uint32* W1Tu = (uint32*)(base + B_W1T);
  uint32* UPb  = (uint32*)(base + B_UPB);
  uint32* H1X  = (uint32*)(base + B_H1X);
  uint32* H2X  = (uint32*)(base + B_H2X);
  uint32* P4X  = (uint32*)(base + B_P4X);
  float*  Y    = (float*)(base + B_Y);
  uint32* H1F  = (uint32*)(base + B_H1F);
  uint32* H2F  = (uint32*)(base + B_H2F);
  uint32* P4F  = (uint32*)(base + B_P4F);

  zero_flags<<<dim3(3), dim3(256), 0, stream>>>(H1F);
  t44_kernel<<<dim3(8192), dim3(256), 0, stream>>>(W2, W3, W2T, W3T);
  t1_kernel<<<dim3(64), dim3(256), 0, stream>>>(W1, W1Tu);
  up_kernel<<<dim3(TSn * 8), dim3(512), 0, stream>>>(J, W1, b1, UPb);
  scan5_kernel<<<dim3(NB), dim3(BLK), 0, stream>>>(
      J, b2, b3, b4, W4, W1Tu, W2T, W3T, UPb,
      H1X, H2X, P4X, H1F, H2F, P4F, Y);
  post_kernel<<<dim3(96), dim3(128), 0, stream>>>(
      J, Pp, UppY, LowY, UppP, LowP, scY, mnY, scP, mnP, Y, out);
}

// Round 9
// 1913.017 us; speedup vs baseline: 2.0810x; 1.1420x over previous
//
#include <hip/hip_runtime.h>

#define NB 256
#define BLK 1024
#define TSn 95
#define DYn 90
#define DPn 80
#define DINn 170
#define Hn 4096

typedef unsigned int uint32;
typedef unsigned long long uint64;

// ---- ws byte offsets ----
#define B_W2T 0ull             // 4096x4096 bf16 transposed (rows of 8KB)
#define B_W3T 33554432ull
#define B_W1T 67108864ull      // 4096 x 48 u32 (bf16x2 per q-pair)
#define B_UPB 67895296ull      // 95 x 2048 u32 (bf16x2)
#define B_H1X 68673536ull      // uint64[2048]: {payload u32, epoch u32}
#define B_H2X 68689920ull      // uint64[2048]
#define B_P4X 68706304ull      // uint64[48][256] slot-major
#define B_Y   68804608ull      // 96 x 96 f32
#define WS_NEED 68841472ull

// out float offsets
#define O_YU 0
#define O_YL 8640
#define O_P1 17280
#define O_PU 24960
#define O_PL 32640

__device__ __forceinline__ uint64 ld_tag(const uint64* p) {
  return __hip_atomic_load(p, __ATOMIC_RELAXED, __HIP_MEMORY_SCOPE_AGENT);
}
__device__ __forceinline__ void st_tag(uint64* p, uint64 v) {
  __hip_atomic_store(p, v, __ATOMIC_RELAXED, __HIP_MEMORY_SCOPE_AGENT);
}
__device__ __forceinline__ unsigned f2bf(float f) {
  uint32 u = __float_as_uint(f);
  return (u + 0x7fffu + ((u >> 16) & 1u)) >> 16;  // RNE
}
__device__ __forceinline__ float bflo(uint32 u) { return __uint_as_float(u << 16); }
__device__ __forceinline__ float bfhi(uint32 u) { return __uint_as_float(u & 0xffff0000u); }

__device__ __forceinline__ float wred(float v) {
#pragma unroll
  for (int o = 32; o > 0; o >>= 1) v += __shfl_xor(v, o, 64);
  return v;
}

// ---------------- prologue kernels (proven R5-R8) ----------------
extern "C" __global__ __launch_bounds__(256)
void t44_kernel(const float* __restrict__ W2, const float* __restrict__ W3,
                uint32* __restrict__ W2T, uint32* __restrict__ W3T) {
  const int mat = blockIdx.x >> 12;
  const int m = blockIdx.x & 4095;
  const float* src = mat ? W3 : W2;
  uint32* dst = mat ? W3T : W2T;
  const int j0 = (m >> 6) * 64, k0 = (m & 63) * 64;
  const int t = threadIdx.x;
  __shared__ float lds[64][65];
  const int jl = t & 63, kb = t >> 6;
#pragma unroll
  for (int i = 0; i < 16; ++i) {
    const int kl = kb + 4 * i;
    lds[kl][jl] = src[(size_t)(k0 + kl) * Hn + j0 + jl];
  }
  __syncthreads();
  const int kp = t & 31, jb = t >> 5;
#pragma unroll
  for (int i = 0; i < 8; ++i) {
    const int jr = jb + 8 * i;
    uint32 v = f2bf(lds[2 * kp][jr]) | (f2bf(lds[2 * kp + 1][jr]) << 16);
    dst[(size_t)(j0 + jr) * 2048 + (k0 >> 1) + kp] = v;
  }
}

// W1 y-part -> W1T[j][48] bf16x2 over q-pairs (zero-pad q>=90).
extern "C" __global__ __launch_bounds__(256)
void t1_kernel(const float* __restrict__ W1, uint32* __restrict__ W1Tu) {
  const int j0 = blockIdx.x * 64;
  const int t = threadIdx.x;
  const int jl = t & 63, q0 = t >> 6;
  for (int qp = q0; qp < 48; qp += 4) {
    float v0 = (2 * qp < DYn) ? W1[(size_t)(2 * qp) * Hn + j0 + jl] : 0.f;
    float v1 = (2 * qp + 1 < DYn) ? W1[(size_t)(2 * qp + 1) * Hn + j0 + jl] : 0.f;
    W1Tu[(size_t)(j0 + jl) * 48 + qp] = f2bf(v0) | (f2bf(v1) << 16);
  }
}

extern "C" __global__ __launch_bounds__(512)
void up_kernel(const float* __restrict__ J, const float* __restrict__ W1,
               const float* __restrict__ b1, uint32* __restrict__ UPb) {
  const int t = blockIdx.x >> 3, jc = blockIdx.x & 7;
  const int j = jc * 512 + threadIdx.x;
  __shared__ float us[DPn];
  __shared__ float oa[512];
  if (threadIdx.x < DPn) us[threadIdx.x] = J[(size_t)t * DINn + DYn + threadIdx.x];
  __syncthreads();
  float acc = b1[j];
#pragma unroll 8
  for (int k = 0; k < DPn; ++k) acc = fmaf(us[k], W1[(size_t)(DYn + k) * Hn + j], acc);
  oa[threadIdx.x] = acc;
  __syncthreads();
  if (threadIdx.x < 256)
    UPb[(size_t)t * 2048 + jc * 256 + threadIdx.x] =
        f2bf(oa[2 * threadIdx.x]) | (f2bf(oa[2 * threadIdx.x + 1]) << 16);
}

// ---------------- scan ----------------
__device__ __forceinline__ float dot_lds(const uint32* __restrict__ Wrow,
                                         const uint32* __restrict__ hvp, int l) {
  float a = 0.f;
#pragma unroll
  for (int i = 0; i < 8; ++i) {
    const uint4 u = *(const uint4*)&Wrow[i * 256 + l * 4];
    const uint4 h = *(const uint4*)&hvp[i * 256 + l * 4];
    a = fmaf(bflo(h.x), bflo(u.x), a); a = fmaf(bfhi(h.x), bfhi(u.x), a);
    a = fmaf(bflo(h.y), bflo(u.y), a); a = fmaf(bfhi(h.y), bfhi(u.y), a);
    a = fmaf(bflo(h.z), bflo(u.z), a); a = fmaf(bfhi(h.z), bfhi(u.z), a);
    a = fmaf(bflo(h.w), bflo(u.w), a); a = fmaf(bfhi(h.w), bfhi(u.w), a);
  }
  return wred(a);
}

__device__ __forceinline__ float dot_pf(const uint4* pf, const uint32* __restrict__ hvp, int l) {
  float a = 0.f;
#pragma unroll
  for (int i = 0; i < 8; ++i) {
    const uint4 h = *(const uint4*)&hvp[i * 256 + l * 4];
    const uint4 u = pf[i];
    a = fmaf(bflo(h.x), bflo(u.x), a); a = fmaf(bfhi(h.x), bfhi(u.x), a);
    a = fmaf(bflo(h.y), bflo(u.y), a); a = fmaf(bfhi(h.y), bfhi(u.y), a);
    a = fmaf(bflo(h.z), bflo(u.z), a); a = fmaf(bfhi(h.z), bfhi(u.z), a);
    a = fmaf(bflo(h.w), bflo(u.w), a); a = fmaf(bfhi(h.w), bfhi(u.w), a);
  }
  return wred(a);
}

// Pull one h-exchange (2048 tagged words) into hvp[] LDS, polling tags.
__device__ __forceinline__ void pull_h(const uint64* __restrict__ X, uint32* __restrict__ hvp,
                                       uint32 tag, int tid) {
  uint64 v0 = ld_tag(X + tid);
  uint64 v1 = ld_tag(X + tid + 1024);
  unsigned spins = 0;
  while ((uint32)(v0 >> 32) != tag || (uint32)(v1 >> 32) != tag) {
    __builtin_amdgcn_s_sleep(1);
    if ((uint32)(v0 >> 32) != tag) v0 = ld_tag(X + tid);
    if ((uint32)(v1 >> 32) != tag) v1 = ld_tag(X + tid + 1024);
    if (++spins > (1u << 22)) break;
  }
  hvp[tid] = (uint32)v0;
  hvp[tid + 1024] = (uint32)v1;
}

extern "C" __global__ __launch_bounds__(BLK, 1)
void scan6_kernel(const float* __restrict__ J, const float* __restrict__ b2,
                  const float* __restrict__ b3, const float* __restrict__ b4,
                  const float* __restrict__ W4, const uint32* __restrict__ W1Tu,
                  const uint32* __restrict__ W2T, const uint32* __restrict__ W3T,
                  const uint32* __restrict__ UPb,
                  uint64* __restrict__ H1X, uint64* __restrict__ H2X,
                  uint64* __restrict__ P4X, float* __restrict__ Y) {
  const int bid = blockIdx.x, tid = threadIdx.x;
  const int w = tid >> 6, l = tid & 63;
  const int j0 = bid * 16, j = j0 + w;

  __shared__ __align__(16) uint32 W2L[16 * 2048];  // this block's 16 W2T rows, resident
  __shared__ __align__(16) uint32 hvp[2048];
  __shared__ float ys[96];
  __shared__ float h1s[16];
  __shared__ float h3L[16];
  __shared__ float y4L[96];

  // one-time stage: W2 rows -> LDS (coalesced, cached loads)
  {
    const uint32* src = W2T + (size_t)j0 * 2048;
    for (int k = tid; k < 32768; k += BLK) W2L[k] = src[k];
  }
  uint4 pf[8];
  __syncthreads();

  for (int t = 0; t <= TSn; ++t) {
    // ---- phase A: y_t (all blocks, symmetric, tagged P4 gather) ----
    if (t == 0) {
      if (tid < DYn) ys[tid] = J[tid];
      __syncthreads();
    } else {
      const uint32 tag = (uint32)t;
#pragma unroll
      for (int ss = 0; ss < 3; ++ss) {
        const int s = w * 3 + ss;
        const uint64* pr = P4X + s * 256 + l * 4;
        uint64 u0 = ld_tag(pr), u1 = ld_tag(pr + 1), u2 = ld_tag(pr + 2), u3 = ld_tag(pr + 3);
        unsigned spins = 0;
        while ((uint32)(u0 >> 32) != tag || (uint32)(u1 >> 32) != tag ||
               (uint32)(u2 >> 32) != tag || (uint32)(u3 >> 32) != tag) {
          __builtin_amdgcn_s_sleep(1);
          if ((uint32)(u0 >> 32) != tag) u0 = ld_tag(pr);
          if ((uint32)(u1 >> 32) != tag) u1 = ld_tag(pr + 1);
          if ((uint32)(u2 >> 32) != tag) u2 = ld_tag(pr + 2);
          if ((uint32)(u3 >> 32) != tag) u3 = ld_tag(pr + 3);
          if (++spins > (1u << 22)) break;
        }
        const uint32 a0 = (uint32)u0, a1 = (uint32)u1, a2 = (uint32)u2, a3 = (uint32)u3;
        float sx = bflo(a0) + bflo(a1) + bflo(a2) + bflo(a3);
        float sy = bfhi(a0) + bfhi(a1) + bfhi(a2) + bfhi(a3);
        sx = wred(sx); sy = wred(sy);
        if (l == 0 && 2 * s < DYn) {
          ys[2 * s] = b4[2 * s] + sx;
          ys[2 * s + 1] = b4[2 * s + 1] + sy;
        }
      }
      __syncthreads();
    }
    if (bid == 0 && tid < DYn) Y[(size_t)t * 96 + tid] = ys[tid];
    if (t == TSn) break;

    // ---- h1 (16 owned cols) + tagged publish (fire-and-forget) ----
    {
      float a = 0.f;
      if (l < 45) {
        uint32 u = W1Tu[(size_t)j * 48 + l];
        a = fmaf(ys[2 * l], bflo(u), ys[2 * l + 1] * bfhi(u));
      }
      a = wred(a);
      if (l == 0) {
        uint32 uu = UPb[(size_t)t * 2048 + (j >> 1)];
        h1s[w] = fmaxf(((j & 1) ? bfhi(uu) : bflo(uu)) + a, 0.f);
      }
    }
    __syncthreads();
    if (tid < 8) {
      uint32 pk = f2bf(h1s[2 * tid]) | (f2bf(h1s[2 * tid + 1]) << 16);
      st_tag(H1X + bid * 8 + tid, (uint64)pk | ((uint64)(t + 1) << 32));
    }

    // ---- phase B: h2 from LDS-resident W2 ----
    {  // issue W3 prefetch BEFORE the poll: hop wait hides the stream
      const uint4* wr3 = (const uint4*)W3T + (size_t)j * 512 + l;
#pragma unroll
      for (int i = 0; i < 8; ++i) pf[i] = wr3[i * 64];
    }
    pull_h(H1X, hvp, (uint32)(t + 1), tid);
    __syncthreads();
    {
      float a = dot_lds(&W2L[w * 2048], hvp, l);
      if (l == 0) h1s[w] = fmaxf(b2[j] + a, 0.f);
    }
    __syncthreads();
    if (tid < 8) {
      uint32 pk = f2bf(h1s[2 * tid]) | (f2bf(h1s[2 * tid + 1]) << 16);
      st_tag(H2X + bid * 8 + tid, (uint64)pk | ((uint64)(t + 1) << 32));
    }

    // ---- phase C: h3 (prefetched W3) + W4 partial -> tagged P4 ----
    pull_h(H2X, hvp, (uint32)(t + 1), tid);
    __syncthreads();
    {
      float a = dot_pf(pf, hvp, l);
      if (l == 0) h3L[w] = fmaxf(b3[j] + a, 0.f);
    }
    __syncthreads();
    if (tid < DYn) {
      float acc = 0.f;
#pragma unroll
      for (int jj = 0; jj < 16; ++jj)
        acc = fmaf(h3L[jj], W4[(size_t)(j0 + jj) * DYn + tid], acc);
      y4L[tid] = acc;
    } else if (tid < 96) {
      y4L[tid] = 0.f;
    }
    __syncthreads();
    if (tid < 48) {
      uint32 pk = f2bf(y4L[2 * tid]) | (f2bf(y4L[2 * tid + 1]) << 16);
      st_tag(P4X + tid * 256 + bid, (uint64)pk | ((uint64)(t + 1) << 32));
    }
  }
}

// ---------------- epilogue ----------------
extern "C" __global__ void post_kernel(const float* __restrict__ J, const float* __restrict__ Pp,
                                       const float* __restrict__ UppY, const float* __restrict__ LowY,
                                       const float* __restrict__ UppP, const float* __restrict__ LowP,
                                       const float* __restrict__ scY, const float* __restrict__ mnY,
                                       const float* __restrict__ scP, const float* __restrict__ mnP,
                                       const float* __restrict__ Y, float* __restrict__ out) {
  const int t = blockIdx.x, k = threadIdx.x;
  if (k < DPn) {
    const float ph = fmaf(J[(size_t)t * DINn + DYn + k], scP[k], mnP[k]);
    out[O_P1 + t * DPn + k] = ph * Pp[t * DPn + k];
    out[O_PU + t * DPn + k] = fmaxf(ph - UppP[t * DPn + k], 0.f);
    out[O_PL + t * DPn + k] = fmaxf(LowP[t * DPn + k] - ph, 0.f);
  }
  if (k < DYn) {
    const float yh = fmaf(Y[(size_t)t * 96 + k], scY[k], mnY[k]);
    out[O_YU + t * DYn + k] = fmaxf(yh - UppY[t * DYn + k], 0.f);
    out[O_YL + t * DYn + k] = fmaxf(LowY[t * DYn + k] - yh, 0.f);
  }
}

extern "C" void kernel_launch(void* const* d_in, const int* in_sizes, int n_in,
                              void* d_out, int out_size, void* d_ws, size_t ws_size,
                              hipStream_t stream) {
  const float* J    = (const float*)d_in[0];
  const float* Pp   = (const float*)d_in[1];
  const float* UppY = (const float*)d_in[2];
  const float* LowY = (const float*)d_in[3];
  const float* UppP = (const float*)d_in[4];
  const float* LowP = (const float*)d_in[5];
  const float* W1   = (const float*)d_in[6];
  const float* b1   = (const float*)d_in[7];
  const float* W2   = (const float*)d_in[8];
  const float* b2   = (const float*)d_in[9];
  const float* W3   = (const float*)d_in[10];
  const float* b3   = (const float*)d_in[11];
  const float* W4   = (const float*)d_in[12];
  const float* b4   = (const float*)d_in[13];
  const float* scY  = (const float*)d_in[14];
  const float* mnY  = (const float*)d_in[15];
  const float* scP  = (const float*)d_in[16];
  const float* mnP  = (const float*)d_in[17];
  float* out = (float*)d_out;

  if (ws_size < WS_NEED) return;

  char* base = (char*)d_ws;
  uint32* W2T  = (uint32*)(base + B_W2T);
  uint32* W3T  = (uint32*)(base + B_W3T);
  uint32* W1Tu = (uint32*)(base + B_W1T);
  uint32* UPb  = (uint32*)(base + B_UPB);
  uint64* H1X  = (uint64*)(base + B_H1X);
  uint64* H2X  = (uint64*)(base + B_H2X);
  uint64* P4X  = (uint64*)(base + B_P4X);
  float*  Y    = (float*)(base + B_Y);

  t44_kernel<<<dim3(8192), dim3(256), 0, stream>>>(W2, W3, W2T, W3T);
  t1_kernel<<<dim3(64), dim3(256), 0, stream>>>(W1, W1Tu);
  up_kernel<<<dim3(TSn * 8), dim3(512), 0, stream>>>(J, W1, b1, UPb);
  scan6_kernel<<<dim3(NB), dim3(BLK), 0, stream>>>(
      J, b2, b3, b4, W4, W1Tu, W2T, W3T, UPb, H1X, H2X, P4X, Y);
  post_kernel<<<dim3(96), dim3(128), 0, stream>>>(
      J, Pp, UppY, LowY, UppP, LowP, scY, mnY, scP, mnP, Y, out);
}

// Round 10
// 1890.242 us; speedup vs baseline: 2.1060x; 1.0120x over previous
//
#include <hip/hip_runtime.h>

#define NB 256
#define BLK 1024
#define TSn 95
#define DYn 90
#define DPn 80
#define DINn 170
#define Hn 4096

typedef unsigned int uint32;
typedef unsigned long long uint64;

// ---- ws byte offsets ----
#define B_W3T 0ull             // 4096x4096 bf16 transposed rows (8KB/row)
#define B_MT  33554432ull      // M = (W1a^T W4^T), same layout as W3T
#define B_UPB 67108864ull      // 95 x 2048 u32 (bf16x2)
#define B_C   67887104ull      // 4096 f32
#define B_H1X 67903488ull      // uint64[2048] tagged
#define B_H2X 67919872ull
#define B_H3X 67936256ull
#define B_H3H 67952640ull      // 95 x 2048 u32 (plain h3 history)
#define WS_NEED 68730880ull    // <= 68841472 proven in R9

// out float offsets
#define O_YU 0
#define O_YL 8640
#define O_P1 17280
#define O_PU 24960
#define O_PL 32640

__device__ __forceinline__ uint64 ld_tag(const uint64* p) {
  return __hip_atomic_load(p, __ATOMIC_RELAXED, __HIP_MEMORY_SCOPE_AGENT);
}
__device__ __forceinline__ void st_tag(uint64* p, uint64 v) {
  __hip_atomic_store(p, v, __ATOMIC_RELAXED, __HIP_MEMORY_SCOPE_AGENT);
}
__device__ __forceinline__ unsigned f2bf(float f) {
  uint32 u = __float_as_uint(f);
  return (u + 0x7fffu + ((u >> 16) & 1u)) >> 16;  // RNE
}
__device__ __forceinline__ float bflo(uint32 u) { return __uint_as_float(u << 16); }
__device__ __forceinline__ float bfhi(uint32 u) { return __uint_as_float(u & 0xffff0000u); }

__device__ __forceinline__ float wred(float v) {
#pragma unroll
  for (int o = 32; o > 0; o >>= 1) v += __shfl_xor(v, o, 64);
  return v;
}

// ---------------- prologue kernels ----------------
// W3 f32 -> bf16x2 transposed rows (proven t44 body, single matrix).
extern "C" __global__ __launch_bounds__(256)
void t3_kernel(const float* __restrict__ W3, uint32* __restrict__ W3T) {
  const int m = blockIdx.x;
  const int j0 = (m >> 6) * 64, k0 = (m & 63) * 64;
  const int t = threadIdx.x;
  __shared__ float lds[64][65];
  const int jl = t & 63, kb = t >> 6;
#pragma unroll
  for (int i = 0; i < 16; ++i) {
    const int kl = kb + 4 * i;
    lds[kl][jl] = W3[(size_t)(k0 + kl) * Hn + j0 + jl];
  }
  __syncthreads();
  const int kp = t & 31, jb = t >> 5;
#pragma unroll
  for (int i = 0; i < 8; ++i) {
    const int jr = jb + 8 * i;
    uint32 v = f2bf(lds[2 * kp][jr]) | (f2bf(lds[2 * kp + 1][jr]) << 16);
    W3T[(size_t)(j0 + jr) * 2048 + (k0 >> 1) + kp] = v;
  }
}

// M[j][k] = sum_{q<90} W1[q][j] * W4[k][q], bf16x2-packed rows like W3T.
extern "C" __global__ __launch_bounds__(256)
void m_kernel(const float* __restrict__ W1, const float* __restrict__ W4,
              uint32* __restrict__ MT) {
  const int j0 = (blockIdx.x >> 6) * 64, k0 = (blockIdx.x & 63) * 64;
  const int tid = threadIdx.x;
  __shared__ float aW[90][64];
  __shared__ float bW[64][90];
  for (int i = tid; i < 90 * 64; i += 256) {
    const int q = i >> 6, jl = i & 63;
    aW[q][jl] = W1[(size_t)q * Hn + j0 + jl];
  }
  for (int i = tid; i < 64 * 90; i += 256) {
    const int kl = i / 90, q = i - kl * 90;
    bW[kl][q] = W4[(size_t)(k0 + kl) * DYn + q];
  }
  __syncthreads();
  const int kpl = tid & 31, jb = tid >> 5;
#pragma unroll
  for (int p = 0; p < 8; ++p) {
    const int jl = p * 8 + jb;
    float m0 = 0.f, m1 = 0.f;
    for (int q = 0; q < DYn; ++q) {
      const float a = aW[q][jl];
      m0 = fmaf(a, bW[2 * kpl][q], m0);
      m1 = fmaf(a, bW[2 * kpl + 1][q], m1);
    }
    MT[(size_t)(j0 + jl) * 2048 + (k0 >> 1) + kpl] = f2bf(m0) | (f2bf(m1) << 16);
  }
}

// c[j] = sum_{q<90} b4[q] * W1[q][j]
extern "C" __global__ __launch_bounds__(256)
void c_kernel(const float* __restrict__ W1, const float* __restrict__ b4,
              float* __restrict__ c) {
  const int j = blockIdx.x * 256 + threadIdx.x;
  float a = 0.f;
#pragma unroll 6
  for (int q = 0; q < DYn; ++q) a = fmaf(b4[q], W1[(size_t)q * Hn + j], a);
  c[j] = a;
}

// UP[t][j] = b1[j] + u_t . W1[90:170][j], bf16x2-packed (proven R7-R9).
extern "C" __global__ __launch_bounds__(512)
void up_kernel(const float* __restrict__ J, const float* __restrict__ W1,
               const float* __restrict__ b1, uint32* __restrict__ UPb) {
  const int t = blockIdx.x >> 3, jc = blockIdx.x & 7;
  const int j = jc * 512 + threadIdx.x;
  __shared__ float us[DPn];
  __shared__ float oa[512];
  if (threadIdx.x < DPn) us[threadIdx.x] = J[(size_t)t * DINn + DYn + threadIdx.x];
  __syncthreads();
  float acc = b1[j];
#pragma unroll 8
  for (int k = 0; k < DPn; ++k) acc = fmaf(us[k], W1[(size_t)(DYn + k) * Hn + j], acc);
  oa[threadIdx.x] = acc;
  __syncthreads();
  if (threadIdx.x < 256)
    UPb[(size_t)t * 2048 + jc * 256 + threadIdx.x] =
        f2bf(oa[2 * threadIdx.x]) | (f2bf(oa[2 * threadIdx.x + 1]) << 16);
}

// ---------------- scan ----------------
__device__ __forceinline__ float dot_lds(const uint32* __restrict__ Wrow,
                                         const uint32* __restrict__ hvp, int l) {
  float a = 0.f;
#pragma unroll
  for (int i = 0; i < 8; ++i) {
    const uint4 u = *(const uint4*)&Wrow[i * 256 + l * 4];
    const uint4 h = *(const uint4*)&hvp[i * 256 + l * 4];
    a = fmaf(bflo(h.x), bflo(u.x), a); a = fmaf(bfhi(h.x), bfhi(u.x), a);
    a = fmaf(bflo(h.y), bflo(u.y), a); a = fmaf(bfhi(h.y), bfhi(u.y), a);
    a = fmaf(bflo(h.z), bflo(u.z), a); a = fmaf(bfhi(h.z), bfhi(u.z), a);
    a = fmaf(bflo(h.w), bflo(u.w), a); a = fmaf(bfhi(h.w), bfhi(u.w), a);
  }
  return wred(a);
}

__device__ __forceinline__ float dot_pf(const uint4* pf, const uint32* __restrict__ hvp, int l) {
  float a = 0.f;
#pragma unroll
  for (int i = 0; i < 8; ++i) {
    const uint4 h = *(const uint4*)&hvp[i * 256 + l * 4];
    const uint4 u = pf[i];
    a = fmaf(bflo(h.x), bflo(u.x), a); a = fmaf(bfhi(h.x), bfhi(u.x), a);
    a = fmaf(bflo(h.y), bflo(u.y), a); a = fmaf(bfhi(h.y), bfhi(u.y), a);
    a = fmaf(bflo(h.z), bflo(u.z), a); a = fmaf(bfhi(h.z), bfhi(u.z), a);
    a = fmaf(bflo(h.w), bflo(u.w), a); a = fmaf(bfhi(h.w), bfhi(u.w), a);
  }
  return wred(a);
}

// Pull one tagged h-exchange (2048 u64) into hvp[] LDS (proven R9).
__device__ __forceinline__ void pull_h(const uint64* __restrict__ X, uint32* __restrict__ hvp,
                                       uint32 tag, int tid) {
  uint64 v0 = ld_tag(X + tid);
  uint64 v1 = ld_tag(X + tid + 1024);
  unsigned spins = 0;
  while ((uint32)(v0 >> 32) != tag || (uint32)(v1 >> 32) != tag) {
    __builtin_amdgcn_s_sleep(1);
    if ((uint32)(v0 >> 32) != tag) v0 = ld_tag(X + tid);
    if ((uint32)(v1 >> 32) != tag) v1 = ld_tag(X + tid + 1024);
    if (++spins > (1u << 22)) break;
  }
  hvp[tid] = (uint32)v0;
  hvp[tid + 1024] = (uint32)v1;
}

extern "C" __global__ __launch_bounds__(BLK, 1)
void scan7_kernel(const float* __restrict__ J, const float* __restrict__ b2,
                  const float* __restrict__ b3, const float* __restrict__ W1,
                  const float* __restrict__ W2, const uint32* __restrict__ W3T,
                  const uint32* __restrict__ MT, const uint32* __restrict__ UPb,
                  const float* __restrict__ cv,
                  uint64* __restrict__ H1X, uint64* __restrict__ H2X,
                  uint64* __restrict__ H3X, uint32* __restrict__ H3H) {
  const int bid = blockIdx.x, tid = threadIdx.x;
  const int w = tid >> 6, l = tid & 63;
  const int j0 = bid * 16, j = j0 + w;

  __shared__ __align__(16) uint32 W2L[16 * 2048];  // this block's 16 W2 columns, bf16x2
  __shared__ __align__(16) uint32 hvp[2048];
  __shared__ float h1s[16];
  __shared__ float ysA[96];

  // one-time stage: W2 columns j0..j0+15 from natural layout (64B-contiguous chunks)
  for (int kp = tid; kp < 2048; kp += BLK) {
    const float* r0 = W2 + (size_t)(2 * kp) * Hn + j0;
    const float* r1 = r0 + Hn;
#pragma unroll
    for (int q = 0; q < 4; ++q) {
      const float4 a4 = *(const float4*)(r0 + 4 * q);
      const float4 c4 = *(const float4*)(r1 + 4 * q);
      W2L[(4 * q + 0) * 2048 + kp] = f2bf(a4.x) | (f2bf(c4.x) << 16);
      W2L[(4 * q + 1) * 2048 + kp] = f2bf(a4.y) | (f2bf(c4.y) << 16);
      W2L[(4 * q + 2) * 2048 + kp] = f2bf(a4.z) | (f2bf(c4.z) << 16);
      W2L[(4 * q + 3) * 2048 + kp] = f2bf(a4.w) | (f2bf(c4.w) << 16);
    }
  }
  uint4 pf[8];
  __syncthreads();

  for (int t = 0; t < TSn; ++t) {
    // ---- phase A: h1 ----
    if (t == 0) {
      if (tid < DYn) ysA[tid] = J[tid];
      __syncthreads();
      float a = 0.f;
      if (l < DYn) a = ysA[l] * W1[(size_t)l * Hn + j];
      if (l + 64 < DYn) a = fmaf(ysA[l + 64], W1[(size_t)(l + 64) * Hn + j], a);
      a = wred(a);
      if (l == 0) {
        const uint32 uu = UPb[(j >> 1)];
        h1s[w] = fmaxf(((j & 1) ? bfhi(uu) : bflo(uu)) + a, 0.f);
      }
    } else {
      pull_h(H3X, hvp, (uint32)t, tid);  // h3 of step t-1 carries tag t
      __syncthreads();
      const float a = dot_pf(pf, hvp, l);  // pf = M row (issued in C of t-1)
      if (l == 0) {
        const uint32 uu = UPb[(size_t)t * 2048 + (j >> 1)];
        h1s[w] = fmaxf(((j & 1) ? bfhi(uu) : bflo(uu)) + cv[j] + a, 0.f);
      }
    }
    __syncthreads();
    if (tid < 8) {
      const uint32 pk = f2bf(h1s[2 * tid]) | (f2bf(h1s[2 * tid + 1]) << 16);
      st_tag(H1X + bid * 8 + tid, (uint64)pk | ((uint64)(t + 1) << 32));
    }

    // issue W3 row prefetch (hides under the H1 poll)
    {
      const uint4* wr = (const uint4*)W3T + (size_t)j * 512 + l;
#pragma unroll
      for (int i = 0; i < 8; ++i) pf[i] = wr[i * 64];
    }

    // ---- phase B: h2 from LDS-resident W2 ----
    pull_h(H1X, hvp, (uint32)(t + 1), tid);
    __syncthreads();
    {
      const float a = dot_lds(&W2L[w * 2048], hvp, l);
      if (l == 0) h1s[w] = fmaxf(b2[j] + a, 0.f);
    }
    __syncthreads();
    if (tid < 8) {
      const uint32 pk = f2bf(h1s[2 * tid]) | (f2bf(h1s[2 * tid + 1]) << 16);
      st_tag(H2X + bid * 8 + tid, (uint64)pk | ((uint64)(t + 1) << 32));
    }

    // ---- phase C: h3 from prefetched W3, publish tagged + history ----
    pull_h(H2X, hvp, (uint32)(t + 1), tid);
    __syncthreads();
    {
      const float a = dot_pf(pf, hvp, l);
      if (l == 0) h1s[w] = fmaxf(b3[j] + a, 0.f);
    }
    __syncthreads();
    if (tid < 8) {
      const uint32 pk = f2bf(h1s[2 * tid]) | (f2bf(h1s[2 * tid + 1]) << 16);
      st_tag(H3X + bid * 8 + tid, (uint64)pk | ((uint64)(t + 1) << 32));
      H3H[(size_t)t * 2048 + bid * 8 + tid] = pk;  // plain store for post pass
    }

    // issue M row prefetch for next step's phase A (hides under H3 poll)
    {
      const uint4* wr = (const uint4*)MT + (size_t)j * 512 + l;
#pragma unroll
      for (int i = 0; i < 8; ++i) pf[i] = wr[i * 64];
    }
  }
}

// ---------------- epilogue: reconstruct y_t from h3 history + objectives ----------------
extern "C" __global__ __launch_bounds__(1024)
void post2_kernel(const float* __restrict__ J, const float* __restrict__ Pp,
                  const float* __restrict__ UppY, const float* __restrict__ LowY,
                  const float* __restrict__ UppP, const float* __restrict__ LowP,
                  const float* __restrict__ W4, const float* __restrict__ b4,
                  const float* __restrict__ scY, const float* __restrict__ mnY,
                  const float* __restrict__ scP, const float* __restrict__ mnP,
                  const uint32* __restrict__ H3H, float* __restrict__ out) {
  const int t = blockIdx.x, tid = threadIdx.x;
  __shared__ float h3s[4096];
  __shared__ float ps[8][128];
  __shared__ float ysv[96];
  if (t > 0) {
    for (int i = tid; i < 2048; i += 1024) {
      const uint32 u = H3H[(size_t)(t - 1) * 2048 + i];
      h3s[2 * i] = bflo(u);
      h3s[2 * i + 1] = bfhi(u);
    }
    __syncthreads();
    const int p = tid >> 7, d = tid & 127;
    if (d < DYn) {
      float a = 0.f;
      const float* wp = W4 + d;
      const int k0 = p * 512;
#pragma unroll 8
      for (int k = k0; k < k0 + 512; ++k) a = fmaf(h3s[k], wp[(size_t)k * DYn], a);
      ps[p][d] = a;
    }
    __syncthreads();
    if (tid < DYn) {
      float s = b4[tid];
#pragma unroll
      for (int p2 = 0; p2 < 8; ++p2) s += ps[p2][tid];
      ysv[tid] = s;
    }
  } else {
    if (tid < DYn) ysv[tid] = J[tid];
  }
  __syncthreads();
  if (tid < DPn) {
    const float ph = fmaf(J[(size_t)t * DINn + DYn + tid], scP[tid], mnP[tid]);
    out[O_P1 + t * DPn + tid] = ph * Pp[t * DPn + tid];
    out[O_PU + t * DPn + tid] = fmaxf(ph - UppP[t * DPn + tid], 0.f);
    out[O_PL + t * DPn + tid] = fmaxf(LowP[t * DPn + tid] - ph, 0.f);
  }
  if (tid < DYn) {
    const float yh = fmaf(ysv[tid], scY[tid], mnY[tid]);
    out[O_YU + t * DYn + tid] = fmaxf(yh - UppY[t * DYn + tid], 0.f);
    out[O_YL + t * DYn + tid] = fmaxf(LowY[t * DYn + tid] - yh, 0.f);
  }
}

extern "C" void kernel_launch(void* const* d_in, const int* in_sizes, int n_in,
                              void* d_out, int out_size, void* d_ws, size_t ws_size,
                              hipStream_t stream) {
  const float* J    = (const float*)d_in[0];
  const float* Pp   = (const float*)d_in[1];
  const float* UppY = (const float*)d_in[2];
  const float* LowY = (const float*)d_in[3];
  const float* UppP = (const float*)d_in[4];
  const float* LowP = (const float*)d_in[5];
  const float* W1   = (const float*)d_in[6];
  const float* b1   = (const float*)d_in[7];
  const float* W2   = (const float*)d_in[8];
  const float* b2   = (const float*)d_in[9];
  const float* W3   = (const float*)d_in[10];
  const float* b3   = (const float*)d_in[11];
  const float* W4   = (const float*)d_in[12];
  const float* b4   = (const float*)d_in[13];
  const float* scY  = (const float*)d_in[14];
  const float* mnY  = (const float*)d_in[15];
  const float* scP  = (const float*)d_in[16];
  const float* mnP  = (const float*)d_in[17];
  float* out = (float*)d_out;

  if (ws_size < WS_NEED) return;

  char* base = (char*)d_ws;
  uint32* W3T = (uint32*)(base + B_W3T);
  uint32* MT  = (uint32*)(base + B_MT);
  uint32* UPb = (uint32*)(base + B_UPB);
  float*  cv  = (float*)(base + B_C);
  uint64* H1X = (uint64*)(base + B_H1X);
  uint64* H2X = (uint64*)(base + B_H2X);
  uint64* H3X = (uint64*)(base + B_H3X);
  uint32* H3H = (uint32*)(base + B_H3H);

  t3_kernel<<<dim3(4096), dim3(256), 0, stream>>>(W3, W3T);
  m_kernel<<<dim3(4096), dim3(256), 0, stream>>>(W1, W4, MT);
  c_kernel<<<dim3(16), dim3(256), 0, stream>>>(W1, b4, cv);
  up_kernel<<<dim3(TSn * 8), dim3(512), 0, stream>>>(J, W1, b1, UPb);
  scan7_kernel<<<dim3(NB), dim3(BLK), 0, stream>>>(
      J, b2, b3, W1, W2, W3T, MT, UPb, cv, H1X, H2X, H3X, H3H);
  post2_kernel<<<dim3(96), dim3(1024), 0, stream>>>(
      J, Pp, UppY, LowY, UppP, LowP, W4, b4, scY, mnY, scP, mnP, H3H, out);
}

// Round 11
// 1152.471 us; speedup vs baseline: 3.4542x; 1.6402x over previous
//
#include <hip/hip_runtime.h>

#define NB 256
#define BLK 1024
#define TSn 95
#define DYn 90
#define DPn 80
#define DINn 170
#define Hn 4096

typedef unsigned int uint32;
typedef unsigned long long uint64;

// ---- ws byte offsets ----
#define B_W3T 0ull             // 4096x4096 bf16 transposed rows (8KB/row)
#define B_MT  33554432ull      // M = (W1a^T W4^T), same layout as W3T
#define B_UPB 67108864ull      // 95 x 2048 u32 (bf16x2)
#define B_C   67887104ull      // 4096 f32
#define B_H1X 67903488ull      // uint64[2048] tagged
#define B_H2X 67919872ull
#define B_H3X 67936256ull
#define B_H3H 67952640ull      // 95 x 2048 u32 (plain h3 history)
#define WS_NEED 68730880ull    // <= 68841472 proven in R9

// out float offsets
#define O_YU 0
#define O_YL 8640
#define O_P1 17280
#define O_PU 24960
#define O_PL 32640

__device__ __forceinline__ uint64 ld_tag(const uint64* p) {
  return __hip_atomic_load(p, __ATOMIC_RELAXED, __HIP_MEMORY_SCOPE_AGENT);
}
__device__ __forceinline__ void st_tag(uint64* p, uint64 v) {
  __hip_atomic_store(p, v, __ATOMIC_RELAXED, __HIP_MEMORY_SCOPE_AGENT);
}
__device__ __forceinline__ unsigned f2bf(float f) {
  uint32 u = __float_as_uint(f);
  return (u + 0x7fffu + ((u >> 16) & 1u)) >> 16;  // RNE
}
__device__ __forceinline__ float bflo(uint32 u) { return __uint_as_float(u << 16); }
__device__ __forceinline__ float bfhi(uint32 u) { return __uint_as_float(u & 0xffff0000u); }

__device__ __forceinline__ float wred(float v) {
#pragma unroll
  for (int o = 32; o > 0; o >>= 1) v += __shfl_xor(v, o, 64);
  return v;
}

// ---------------- prologue kernels ----------------
// W3 f32 -> bf16x2 transposed rows (proven R5-R10).
extern "C" __global__ __launch_bounds__(256)
void t3_kernel(const float* __restrict__ W3, uint32* __restrict__ W3T) {
  const int m = blockIdx.x;
  const int j0 = (m >> 6) * 64, k0 = (m & 63) * 64;
  const int t = threadIdx.x;
  __shared__ float lds[64][65];
  const int jl = t & 63, kb = t >> 6;
#pragma unroll
  for (int i = 0; i < 16; ++i) {
    const int kl = kb + 4 * i;
    lds[kl][jl] = W3[(size_t)(k0 + kl) * Hn + j0 + jl];
  }
  __syncthreads();
  const int kp = t & 31, jb = t >> 5;
#pragma unroll
  for (int i = 0; i < 8; ++i) {
    const int jr = jb + 8 * i;
    uint32 v = f2bf(lds[2 * kp][jr]) | (f2bf(lds[2 * kp + 1][jr]) << 16);
    W3T[(size_t)(j0 + jr) * 2048 + (k0 >> 1) + kp] = v;
  }
}

// M[j][k] = sum_{q<90} W1[q][j] * W4[k][q] -> bf16x2 rows.
// Register-blocked outer product: 4x4 acc/thread, float4 LDS reads
// (broadcast + 2-way only), 180 LDS ops/thread (was 2160 scalar, 4-way).
extern "C" __global__ __launch_bounds__(256)
void m_kernel(const float* __restrict__ W1, const float* __restrict__ W4,
              uint32* __restrict__ MT) {
  const int j0 = (blockIdx.x >> 6) * 64, k0 = (blockIdx.x & 63) * 64;
  const int tid = threadIdx.x;
  __shared__ __align__(16) float aW[90][64];  // aW[q][jl] = W1[q][j0+jl]
  __shared__ __align__(16) float bT[90][64];  // bT[q][kl] = W4[(k0+kl)][q]
  for (int i = tid; i < 90 * 64; i += 256) {
    const int q = i >> 6, jl = i & 63;
    aW[q][jl] = W1[(size_t)q * Hn + j0 + jl];          // coalesced rows
  }
  for (int i = tid; i < 90 * 64; i += 256) {
    const int q = i >> 6, kl = i & 63;
    bT[q][kl] = W4[(size_t)(k0 + kl) * DYn + q];       // scatter read, clean LDS write
  }
  __syncthreads();
  const int ty = tid >> 4, tx = tid & 15;              // 4x4 tile at (j0+4ty, k0+4tx)
  float acc[4][4] = {};
#pragma unroll 2
  for (int q = 0; q < DYn; ++q) {
    const float4 av = *(const float4*)&aW[q][ty * 4];
    const float4 bv = *(const float4*)&bT[q][tx * 4];
    const float ar[4] = {av.x, av.y, av.z, av.w};
    const float br[4] = {bv.x, bv.y, bv.z, bv.w};
#pragma unroll
    for (int r = 0; r < 4; ++r)
#pragma unroll
      for (int c = 0; c < 4; ++c) acc[r][c] = fmaf(ar[r], br[c], acc[r][c]);
  }
#pragma unroll
  for (int r = 0; r < 4; ++r) {
    const size_t row = (size_t)(j0 + ty * 4 + r) * 2048 + (k0 >> 1) + tx * 2;
#pragma unroll
    for (int c = 0; c < 2; ++c)
      MT[row + c] = f2bf(acc[r][2 * c]) | (f2bf(acc[r][2 * c + 1]) << 16);
  }
}

// c[j] = sum_{q<90} b4[q] * W1[q][j]
extern "C" __global__ __launch_bounds__(256)
void c_kernel(const float* __restrict__ W1, const float* __restrict__ b4,
              float* __restrict__ c) {
  const int j = blockIdx.x * 256 + threadIdx.x;
  float a = 0.f;
#pragma unroll 6
  for (int q = 0; q < DYn; ++q) a = fmaf(b4[q], W1[(size_t)q * Hn + j], a);
  c[j] = a;
}

// UP[t][j] = b1[j] + u_t . W1[90:170][j], bf16x2-packed (proven R7-R10).
extern "C" __global__ __launch_bounds__(512)
void up_kernel(const float* __restrict__ J, const float* __restrict__ W1,
               const float* __restrict__ b1, uint32* __restrict__ UPb) {
  const int t = blockIdx.x >> 3, jc = blockIdx.x & 7;
  const int j = jc * 512 + threadIdx.x;
  __shared__ float us[DPn];
  __shared__ float oa[512];
  if (threadIdx.x < DPn) us[threadIdx.x] = J[(size_t)t * DINn + DYn + threadIdx.x];
  __syncthreads();
  float acc = b1[j];
#pragma unroll 8
  for (int k = 0; k < DPn; ++k) acc = fmaf(us[k], W1[(size_t)(DYn + k) * Hn + j], acc);
  oa[threadIdx.x] = acc;
  __syncthreads();
  if (threadIdx.x < 256)
    UPb[(size_t)t * 2048 + jc * 256 + threadIdx.x] =
        f2bf(oa[2 * threadIdx.x]) | (f2bf(oa[2 * threadIdx.x + 1]) << 16);
}

// ---------------- scan (unchanged from R10) ----------------
__device__ __forceinline__ float dot_lds(const uint32* __restrict__ Wrow,
                                         const uint32* __restrict__ hvp, int l) {
  float a = 0.f;
#pragma unroll
  for (int i = 0; i < 8; ++i) {
    const uint4 u = *(const uint4*)&Wrow[i * 256 + l * 4];
    const uint4 h = *(const uint4*)&hvp[i * 256 + l * 4];
    a = fmaf(bflo(h.x), bflo(u.x), a); a = fmaf(bfhi(h.x), bfhi(u.x), a);
    a = fmaf(bflo(h.y), bflo(u.y), a); a = fmaf(bfhi(h.y), bfhi(u.y), a);
    a = fmaf(bflo(h.z), bflo(u.z), a); a = fmaf(bfhi(h.z), bfhi(u.z), a);
    a = fmaf(bflo(h.w), bflo(u.w), a); a = fmaf(bfhi(h.w), bfhi(u.w), a);
  }
  return wred(a);
}

__device__ __forceinline__ float dot_pf(const uint4* pf, const uint32* __restrict__ hvp, int l) {
  float a = 0.f;
#pragma unroll
  for (int i = 0; i < 8; ++i) {
    const uint4 h = *(const uint4*)&hvp[i * 256 + l * 4];
    const uint4 u = pf[i];
    a = fmaf(bflo(h.x), bflo(u.x), a); a = fmaf(bfhi(h.x), bfhi(u.x), a);
    a = fmaf(bflo(h.y), bflo(u.y), a); a = fmaf(bfhi(h.y), bfhi(u.y), a);
    a = fmaf(bflo(h.z), bflo(u.z), a); a = fmaf(bfhi(h.z), bfhi(u.z), a);
    a = fmaf(bflo(h.w), bflo(u.w), a); a = fmaf(bfhi(h.w), bfhi(u.w), a);
  }
  return wred(a);
}

// Pull one tagged h-exchange (2048 u64) into hvp[] LDS (proven R9-R10).
__device__ __forceinline__ void pull_h(const uint64* __restrict__ X, uint32* __restrict__ hvp,
                                       uint32 tag, int tid) {
  uint64 v0 = ld_tag(X + tid);
  uint64 v1 = ld_tag(X + tid + 1024);
  unsigned spins = 0;
  while ((uint32)(v0 >> 32) != tag || (uint32)(v1 >> 32) != tag) {
    __builtin_amdgcn_s_sleep(1);
    if ((uint32)(v0 >> 32) != tag) v0 = ld_tag(X + tid);
    if ((uint32)(v1 >> 32) != tag) v1 = ld_tag(X + tid + 1024);
    if (++spins > (1u << 22)) break;
  }
  hvp[tid] = (uint32)v0;
  hvp[tid + 1024] = (uint32)v1;
}

extern "C" __global__ __launch_bounds__(BLK, 1)
void scan7_kernel(const float* __restrict__ J, const float* __restrict__ b2,
                  const float* __restrict__ b3, const float* __restrict__ W1,
                  const float* __restrict__ W2, const uint32* __restrict__ W3T,
                  const uint32* __restrict__ MT, const uint32* __restrict__ UPb,
                  const float* __restrict__ cv,
                  uint64* __restrict__ H1X, uint64* __restrict__ H2X,
                  uint64* __restrict__ H3X, uint32* __restrict__ H3H) {
  const int bid = blockIdx.x, tid = threadIdx.x;
  const int w = tid >> 6, l = tid & 63;
  const int j0 = bid * 16, j = j0 + w;

  __shared__ __align__(16) uint32 W2L[16 * 2048];  // this block's 16 W2 columns, bf16x2
  __shared__ __align__(16) uint32 hvp[2048];
  __shared__ float h1s[16];
  __shared__ float ysA[96];

  // one-time stage: W2 columns j0..j0+15 from natural layout (64B-contiguous chunks)
  for (int kp = tid; kp < 2048; kp += BLK) {
    const float* r0 = W2 + (size_t)(2 * kp) * Hn + j0;
    const float* r1 = r0 + Hn;
#pragma unroll
    for (int q = 0; q < 4; ++q) {
      const float4 a4 = *(const float4*)(r0 + 4 * q);
      const float4 c4 = *(const float4*)(r1 + 4 * q);
      W2L[(4 * q + 0) * 2048 + kp] = f2bf(a4.x) | (f2bf(c4.x) << 16);
      W2L[(4 * q + 1) * 2048 + kp] = f2bf(a4.y) | (f2bf(c4.y) << 16);
      W2L[(4 * q + 2) * 2048 + kp] = f2bf(a4.z) | (f2bf(c4.z) << 16);
      W2L[(4 * q + 3) * 2048 + kp] = f2bf(a4.w) | (f2bf(c4.w) << 16);
    }
  }
  uint4 pf[8];
  __syncthreads();

  for (int t = 0; t < TSn; ++t) {
    // ---- phase A: h1 ----
    if (t == 0) {
      if (tid < DYn) ysA[tid] = J[tid];
      __syncthreads();
      float a = 0.f;
      if (l < DYn) a = ysA[l] * W1[(size_t)l * Hn + j];
      if (l + 64 < DYn) a = fmaf(ysA[l + 64], W1[(size_t)(l + 64) * Hn + j], a);
      a = wred(a);
      if (l == 0) {
        const uint32 uu = UPb[(j >> 1)];
        h1s[w] = fmaxf(((j & 1) ? bfhi(uu) : bflo(uu)) + a, 0.f);
      }
    } else {
      pull_h(H3X, hvp, (uint32)t, tid);  // h3 of step t-1 carries tag t
      __syncthreads();
      const float a = dot_pf(pf, hvp, l);  // pf = M row (issued in C of t-1)
      if (l == 0) {
        const uint32 uu = UPb[(size_t)t * 2048 + (j >> 1)];
        h1s[w] = fmaxf(((j & 1) ? bfhi(uu) : bflo(uu)) + cv[j] + a, 0.f);
      }
    }
    __syncthreads();
    if (tid < 8) {
      const uint32 pk = f2bf(h1s[2 * tid]) | (f2bf(h1s[2 * tid + 1]) << 16);
      st_tag(H1X + bid * 8 + tid, (uint64)pk | ((uint64)(t + 1) << 32));
    }

    // issue W3 row prefetch (hides under the H1 poll)
    {
      const uint4* wr = (const uint4*)W3T + (size_t)j * 512 + l;
#pragma unroll
      for (int i = 0; i < 8; ++i) pf[i] = wr[i * 64];
    }

    // ---- phase B: h2 from LDS-resident W2 ----
    pull_h(H1X, hvp, (uint32)(t + 1), tid);
    __syncthreads();
    {
      const float a = dot_lds(&W2L[w * 2048], hvp, l);
      if (l == 0) h1s[w] = fmaxf(b2[j] + a, 0.f);
    }
    __syncthreads();
    if (tid < 8) {
      const uint32 pk = f2bf(h1s[2 * tid]) | (f2bf(h1s[2 * tid + 1]) << 16);
      st_tag(H2X + bid * 8 + tid, (uint64)pk | ((uint64)(t + 1) << 32));
    }

    // ---- phase C: h3 from prefetched W3, publish tagged + history ----
    pull_h(H2X, hvp, (uint32)(t + 1), tid);
    __syncthreads();
    {
      const float a = dot_pf(pf, hvp, l);
      if (l == 0) h1s[w] = fmaxf(b3[j] + a, 0.f);
    }
    __syncthreads();
    if (tid < 8) {
      const uint32 pk = f2bf(h1s[2 * tid]) | (f2bf(h1s[2 * tid + 1]) << 16);
      st_tag(H3X + bid * 8 + tid, (uint64)pk | ((uint64)(t + 1) << 32));
      H3H[(size_t)t * 2048 + bid * 8 + tid] = pk;  // plain store for post pass
    }

    // issue M row prefetch for next step's phase A (hides under H3 poll)
    {
      const uint4* wr = (const uint4*)MT + (size_t)j * 512 + l;
#pragma unroll
      for (int i = 0; i < 8; ++i) pf[i] = wr[i * 64];
    }
  }
}

// ---------------- epilogue: reconstruct y_t from h3 history + objectives ----------------
extern "C" __global__ __launch_bounds__(1024)
void post2_kernel(const float* __restrict__ J, const float* __restrict__ Pp,
                  const float* __restrict__ UppY, const float* __restrict__ LowY,
                  const float* __restrict__ UppP, const float* __restrict__ LowP,
                  const float* __restrict__ W4, const float* __restrict__ b4,
                  const float* __restrict__ scY, const float* __restrict__ mnY,
                  const float* __restrict__ scP, const float* __restrict__ mnP,
                  const uint32* __restrict__ H3H, float* __restrict__ out) {
  const int t = blockIdx.x, tid = threadIdx.x;
  __shared__ float h3s[4096];
  __shared__ float ps[8][128];
  __shared__ float ysv[96];
  if (t > 0) {
    for (int i = tid; i < 2048; i += 1024) {
      const uint32 u = H3H[(size_t)(t - 1) * 2048 + i];
      h3s[2 * i] = bflo(u);
      h3s[2 * i + 1] = bfhi(u);
    }
    __syncthreads();
    const int p = tid >> 7, d = tid & 127;
    if (d < DYn) {
      float a = 0.f;
      const float* wp = W4 + d;
      const int k0 = p * 512;
#pragma unroll 8
      for (int k = k0; k < k0 + 512; ++k) a = fmaf(h3s[k], wp[(size_t)k * DYn], a);
      ps[p][d] = a;
    }
    __syncthreads();
    if (tid < DYn) {
      float s = b4[tid];
#pragma unroll
      for (int p2 = 0; p2 < 8; ++p2) s += ps[p2][tid];
      ysv[tid] = s;
    }
  } else {
    if (tid < DYn) ysv[tid] = J[tid];
  }
  __syncthreads();
  if (tid < DPn) {
    const float ph = fmaf(J[(size_t)t * DINn + DYn + tid], scP[tid], mnP[tid]);
    out[O_P1 + t * DPn + tid] = ph * Pp[t * DPn + tid];
    out[O_PU + t * DPn + tid] = fmaxf(ph - UppP[t * DPn + tid], 0.f);
    out[O_PL + t * DPn + tid] = fmaxf(LowP[t * DPn + tid] - ph, 0.f);
  }
  if (tid < DYn) {
    const float yh = fmaf(ysv[tid], scY[tid], mnY[tid]);
    out[O_YU + t * DYn + tid] = fmaxf(yh - UppY[t * DYn + tid], 0.f);
    out[O_YL + t * DYn + tid] = fmaxf(LowY[t * DYn + tid] - yh, 0.f);
  }
}

extern "C" void kernel_launch(void* const* d_in, const int* in_sizes, int n_in,
                              void* d_out, int out_size, void* d_ws, size_t ws_size,
                              hipStream_t stream) {
  const float* J    = (const float*)d_in[0];
  const float* Pp   = (const float*)d_in[1];
  const float* UppY = (const float*)d_in[2];
  const float* LowY = (const float*)d_in[3];
  const float* UppP = (const float*)d_in[4];
  const float* LowP = (const float*)d_in[5];
  const float* W1   = (const float*)d_in[6];
  const float* b1   = (const float*)d_in[7];
  const float* W2   = (const float*)d_in[8];
  const float* b2   = (const float*)d_in[9];
  const float* W3   = (const float*)d_in[10];
  const float* b3   = (const float*)d_in[11];
  const float* W4   = (const float*)d_in[12];
  const float* b4   = (const float*)d_in[13];
  const float* scY  = (const float*)d_in[14];
  const float* mnY  = (const float*)d_in[15];
  const float* scP  = (const float*)d_in[16];
  const float* mnP  = (const float*)d_in[17];
  float* out = (float*)d_out;

  if (ws_size < WS_NEED) return;

  char* base = (char*)d_ws;
  uint32* W3T = (uint32*)(base + B_W3T);
  uint32* MT  = (uint32*)(base + B_MT);
  uint32* UPb = (uint32*)(base + B_UPB);
  float*  cv  = (float*)(base + B_C);
  uint64* H1X = (uint64*)(base + B_H1X);
  uint64* H2X = (uint64*)(base + B_H2X);
  uint64* H3X = (uint64*)(base + B_H3X);
  uint32* H3H = (uint32*)(base + B_H3H);

  t3_kernel<<<dim3(4096), dim3(256), 0, stream>>>(W3, W3T);
  m_kernel<<<dim3(4096), dim3(256), 0, stream>>>(W1, W4, MT);
  c_kernel<<<dim3(16), dim3(256), 0, stream>>>(W1, b4, cv);
  up_kernel<<<dim3(TSn * 8), dim3(512), 0, stream>>>(J, W1, b1, UPb);
  scan7_kernel<<<dim3(NB), dim3(BLK), 0, stream>>>(
      J, b2, b3, W1, W2, W3T, MT, UPb, cv, H1X, H2X, H3X, H3H);
  post2_kernel<<<dim3(96), dim3(1024), 0, stream>>>(
      J, Pp, UppY, LowY, UppP, LowP, W4, b4, scY, mnY, scP, mnP, H3H, out);
}